// Round 11
// baseline (189.112 us; speedup 1.0000x reference)
//
#include <hip/hip_runtime.h>
#include <stdint.h>

#define NB   4
#define SEQ  4096
#define DIM  256
#define NROW (NB*SEQ)   // 16384

using bf16x8   = __attribute__((ext_vector_type(8))) __bf16;
using half8    = __attribute__((ext_vector_type(8))) _Float16;
using f32x4    = __attribute__((ext_vector_type(4))) float;
using f32x16   = __attribute__((ext_vector_type(16))) float;
using u32x4    = __attribute__((ext_vector_type(4))) unsigned int;
using ushort4t = __attribute__((ext_vector_type(4))) unsigned short;

__device__ __forceinline__ unsigned f2bf(float f){
    unsigned u = __builtin_bit_cast(unsigned, f);
    return (u + 0x7fffu + ((u >> 16) & 1u)) >> 16;   // RNE to bf16 bits
}
__device__ __forceinline__ float bf2f(unsigned b){
    return __builtin_bit_cast(float, b << 16);
}

#define MFMA(a,b,c)   __builtin_amdgcn_mfma_f32_16x16x32_bf16((a),(b),(c),0,0,0)
#define MFMAQK(a,b,c) __builtin_amdgcn_mfma_f32_32x32x16_f16((a),(b),(c),0,0,0)
#define MFMAPV(a,b,c) __builtin_amdgcn_mfma_f32_32x32x16_bf16((a),(b),(c),0,0,0)

// async global -> LDS, 16 B per lane. LDS dest = wave-uniform base + lane*16.
__device__ __forceinline__ void gld16(const void* g, void* l){
    __builtin_amdgcn_global_load_lds(
        (const __attribute__((address_space(1))) void*)g,
        (__attribute__((address_space(3))) void*)l, 16, 0, 0);
}

// ---------------------------------------------------------------------------
// Kernel 1: W[k][n] fp32 -> FRAGMENT-ORDERED split bf16 planes.
//   o = ((((m*2+nh)*8+nt)*8+kc)*64 + lane)*8 + j
// ---------------------------------------------------------------------------
__global__ __launch_bounds__(256) void convert_w_kernel(
    const float* __restrict__ Wq, const float* __restrict__ Wk,
    const float* __restrict__ Wv,
    unsigned short* __restrict__ WtHi, unsigned short* __restrict__ WtLo)
{
    int mat = blockIdx.y;
    const float* W = (mat == 0) ? Wq : (mat == 1 ? Wk : Wv);
    int id = blockIdx.x * 256 + threadIdx.x;     // 0..65535
    int k = id >> 8, n = id & 255;
    float v = W[id];                              // W[k][n], coalesced read
    unsigned hi = f2bf(v);
    unsigned lo = f2bf(v - bf2f(hi));
    int nh = n >> 7, nt = (n >> 4) & 7, q16 = n & 15;
    int kc = k >> 5, g = (k >> 3) & 3, j = k & 7;
    int lane = g * 16 + q16;
    int o = ((((mat * 2 + nh) * 8 + nt) * 8 + kc) * 64 + lane) * 8 + j;
    WtHi[o] = (unsigned short)hi;
    WtLo[o] = (unsigned short)lo;
}

// ---------------------------------------------------------------------------
// Kernel 2: fused QKV projection (3-term bf16 split, fp32 accum).
// CHANGE vs R10: W fragments staged per-kc into 48 KB LDS via global_load_lds
// (one copy per block instead of per wave -> 4x L2 traffic cut).
// Emits Qf/Kf fp16 [16384][256], Vt bf16 transposed [b][d][s].
// ---------------------------------------------------------------------------
__global__ __launch_bounds__(256) void proj_kernel(
    const float* __restrict__ x,
    const unsigned short* __restrict__ WtHi, const unsigned short* __restrict__ WtLo,
    const float* __restrict__ bq, const float* __restrict__ bk,
    const float* __restrict__ bv,
    _Float16* __restrict__ Qf, _Float16* __restrict__ Kf,
    unsigned short* __restrict__ Vt)
{
    __shared__ __align__(16) unsigned char wsm[49152];   // 48 frag-slots x 1 KB

    const int tid = threadIdx.x, lane = tid & 63, wid = tid >> 6;
    const int g = lane >> 4, q16 = lane & 15;
    const int mbase = blockIdx.x * 64 + wid * 16;
    const int nh = blockIdx.y;

    f32x4 acc[3][8];
    #pragma unroll
    for (int m = 0; m < 3; m++)
        #pragma unroll
        for (int n = 0; n < 8; n++) acc[m][n] = f32x4{0.f, 0.f, 0.f, 0.f};

    const float* xr = x + (mbase + q16) * DIM;

    for (int kc = 0; kc < 8; kc++) {
        __syncthreads();   // previous iteration's LDS reads complete
        // ---- stage this kc's 48 fragment-KB (3 mats x 8 nt x 2 planes) ----
        #pragma unroll
        for (int i = 0; i < 12; i++) {
            const int idx = wid * 12 + i;            // 0..47 = mat*16+nt*2+pl
            const int mat = idx >> 4, nt = (idx >> 1) & 7, pl = idx & 1;
            const size_t fb =
                ((size_t)(((mat * 2 + nh) * 8 + nt) * 8 + kc)) * 512 + lane * 8;
            gld16((pl ? WtLo : WtHi) + fb, wsm + idx * 1024);
        }

        // ---- x split hi/lo (overlaps the DMA) ----
        const float* p = xr + kc * 32 + 8 * g;
        f32x4 va = *(const f32x4*)p;
        f32x4 vb = *(const f32x4*)(p + 4);
        float fv[8] = {va[0], va[1], va[2], va[3], vb[0], vb[1], vb[2], vb[3]};
        unsigned hw[4], lw[4];
        #pragma unroll
        for (int i = 0; i < 4; i++) {
            unsigned h0 = f2bf(fv[2*i]),              h1 = f2bf(fv[2*i+1]);
            unsigned l0 = f2bf(fv[2*i]   - bf2f(h0)), l1 = f2bf(fv[2*i+1] - bf2f(h1));
            hw[i] = h0 | (h1 << 16);
            lw[i] = l0 | (l1 << 16);
        }
        bf16x8 ahi = __builtin_bit_cast(bf16x8, u32x4{hw[0], hw[1], hw[2], hw[3]});
        bf16x8 alo = __builtin_bit_cast(bf16x8, u32x4{lw[0], lw[1], lw[2], lw[3]});

        __syncthreads();   // DMA landed (barrier drains vmcnt)

        #pragma unroll
        for (int mat = 0; mat < 3; mat++) {
            #pragma unroll
            for (int nt = 0; nt < 8; nt++) {
                const int sidx = mat * 16 + nt * 2;
                bf16x8 bh = *(const bf16x8*)(wsm + sidx * 1024 + lane * 16);
                bf16x8 bl = *(const bf16x8*)(wsm + (sidx + 1) * 1024 + lane * 16);
                acc[mat][nt] = MFMA(ahi, bh, acc[mat][nt]);
                acc[mat][nt] = MFMA(ahi, bl, acc[mat][nt]);
                acc[mat][nt] = MFMA(alo, bh, acc[mat][nt]);
            }
        }
    }

    #pragma unroll
    for (int nt = 0; nt < 8; nt++) {
        int ncol = nh * 128 + nt * 16 + q16;
        {   // Q -> fp16
            float bb = bq[ncol];
            f32x4 c = acc[0][nt];
            #pragma unroll
            for (int r = 0; r < 4; r++)
                Qf[(size_t)(mbase + 4*g + r) * DIM + ncol] = (_Float16)(c[r] + bb);
        }
        {   // K -> fp16
            float bb = bk[ncol];
            f32x4 c = acc[1][nt];
            #pragma unroll
            for (int r = 0; r < 4; r++)
                Kf[(size_t)(mbase + 4*g + r) * DIM + ncol] = (_Float16)(c[r] + bb);
        }
        {   // V -> plain transposed bf16 Vt[b][d][s]
            float bb = bv[ncol];
            f32x4 c = acc[2][nt];
            ushort4t pk;
            #pragma unroll
            for (int r = 0; r < 4; r++) pk[r] = (unsigned short)f2bf(c[r] + bb);
            int m0 = mbase + 4 * g;
            int bat = m0 >> 12, s0 = m0 & 4095;
            *(ushort4t*)(Vt + (size_t)(bat * DIM + ncol) * SEQ + s0) = pk;
        }
    }
}

// ---------------------------------------------------------------------------
// Kernel 3: flash attention, 32x32 MFMA, fp16 QK^T, bf16 PV.
// 8 waves x 32 q-rows = 256 rows/block. grid (64 qtiles, 4 splits) = 256
// blocks = 1/CU. KVBLK=64, wave-staggered sub-tile order (R10).
// CHANGE vs R10: QK^T uses 2 independent MFMA chains (even/odd s) to halve
// the serial accumulator-dependency stall; summed at end (fp32 reorder only).
// LDS: K 32KB + V 32KB per buffer, double-buffered.
// ---------------------------------------------------------------------------
#define KLDS  0
#define VLDS  32768
#define BUFSZ 65536

__global__ __launch_bounds__(512, 1) void flash_kernel(
    const _Float16* __restrict__ Qf, const _Float16* __restrict__ Kf,
    const unsigned short* __restrict__ Vt,
    unsigned short* __restrict__ O0, unsigned short* __restrict__ O1,
    unsigned short* __restrict__ O2, unsigned short* __restrict__ O3,
    float2* __restrict__ ml0, float2* __restrict__ ml1,
    float2* __restrict__ ml2, float2* __restrict__ ml3)
{
    __shared__ __align__(16) unsigned char smem[131072];

    const int tid = threadIdx.x, lane = tid & 63, wid = tid >> 6;
    const int r32 = lane & 31, h = lane >> 5;
    const int qrow0 = blockIdx.x * 256;
    const int b = qrow0 >> 12;
    const int split = blockIdx.y;
    const int kvbase = split * 1024;
    const int stp = wid & 1;          // sub-tile phase stagger per wave

    // --- Q fragments: B-operand, col q = r32, k = 16s + 8h + j ---
    half8 qf[16];
    {
        const _Float16* qp = Qf + (size_t)(qrow0 + wid * 32 + r32) * DIM;
        #pragma unroll
        for (int s = 0; s < 16; s++)
            qf[s] = *(const half8*)(qp + s * 16 + h * 8);
    }

    f32x16 o[8];
    #pragma unroll
    for (int i = 0; i < 8; i++)
        #pragma unroll
        for (int j = 0; j < 16; j++) o[i][j] = 0.f;
    float m_run = -3.0e38f, l_run = 0.f;

    // ---- staging: 8 x global_load_lds per wave per KVBLK (64 total) ----
    auto stage = [&](int chunk, int buf) {
        const int kv0 = kvbase + chunk * 64;
        unsigned char* base = smem + buf * BUFSZ;
        #pragma unroll
        for (int i = 0; i < 4; i++) {
            const int t = wid * 4 + i;                 // 0..31
            // K fp16 [64 rows][512B]; instr t covers rows 2t,2t+1
            const int krow = 2 * t + h;
            const int ksl  = (lane & 31) ^ (krow & 7);
            gld16(Kf + (size_t)(b * SEQ + kv0 + krow) * DIM + ksl * 8,
                  base + KLDS + t * 1024);
            // V bf16 [256 d][128B]; instr t covers d 8t..8t+7
            const int d   = 8 * t + (lane >> 3);
            const int vsl = (lane & 7) ^ (d & 7);
            gld16(Vt + (size_t)(b * DIM + d) * SEQ + kv0 + vsl * 8,
                  base + VLDS + t * 1024);
        }
    };

    stage(0, 0);
    __syncthreads();

    for (int c = 0; c < 16; c++) {
        const int bf = c & 1;
        if (c + 1 < 16) stage(c + 1, bf ^ 1);

        const unsigned char* kb = smem + bf * BUFSZ;
        const unsigned char* vb = kb + VLDS;

        // ---- two 32-kv sub-tiles; order staggered across waves ----
        #pragma unroll
        for (int ii = 0; ii < 2; ii++) {
            const int st = ii ^ stp;
            // QK^T: A = K rows (kv), B = Q (cols=q); 2 indep chains
            f32x16 a0, a1;
            #pragma unroll
            for (int j = 0; j < 16; j++) { a0[j] = 0.f; a1[j] = 0.f; }
            __builtin_amdgcn_s_setprio(1);
            #pragma unroll
            for (int s = 0; s < 16; s += 2) {
                const int rb = (st * 32 + r32) * 512;
                const int off0 = rb + (((2 * s + h)     ^ (r32 & 7)) * 16);
                const int off1 = rb + (((2 * s + 2 + h) ^ (r32 & 7)) * 16);
                half8 kf0 = *(const half8*)(kb + KLDS + off0);
                half8 kf1 = *(const half8*)(kb + KLDS + off1);
                a0 = MFMAQK(kf0, qf[s],     a0);
                a1 = MFMAQK(kf1, qf[s + 1], a1);
            }
            __builtin_amdgcn_s_setprio(0);
            f32x16 a = a0 + a1;
            // lane holds S[kv=(j&3)+8*(j>>2)+4h (+32*st)][q=r32] in a[j]

            // online softmax (per q-column; halves reduced via xor-32)
            float pm = a[0];
            #pragma unroll
            for (int j = 1; j < 16; j++) pm = fmaxf(pm, a[j]);
            pm = fmaxf(pm, __shfl_xor(pm, 32, 64));
            const bool defer = __all(pm <= m_run + 8.0f) != 0;
            const float mn = defer ? m_run : fmaxf(m_run, pm);
            const float sc = defer ? 1.0f : __expf(m_run - mn);
            float e[16]; float ps = 0.f;
            #pragma unroll
            for (int j = 0; j < 16; j++) { e[j] = __expf(a[j] - mn); ps += e[j]; }
            ps += __shfl_xor(ps, 32, 64);
            l_run = l_run * sc + ps;
            m_run = mn;

            // P -> bf16 B-fragments via cvt_pk + permlane32_swap
            unsigned w[8];
            #pragma unroll
            for (int t = 0; t < 8; t++)
                asm("v_cvt_pk_bf16_f32 %0, %1, %2"
                    : "=v"(w[t]) : "v"(e[2 * t]), "v"(e[2 * t + 1]));
            asm volatile("v_permlane32_swap_b32 %0, %1" : "+v"(w[0]), "+v"(w[2]));
            asm volatile("v_permlane32_swap_b32 %0, %1" : "+v"(w[1]), "+v"(w[3]));
            asm volatile("v_permlane32_swap_b32 %0, %1" : "+v"(w[4]), "+v"(w[6]));
            asm volatile("v_permlane32_swap_b32 %0, %1" : "+v"(w[5]), "+v"(w[7]));
            bf16x8 pA = __builtin_bit_cast(bf16x8, u32x4{w[0], w[1], w[2], w[3]});
            bf16x8 pB = __builtin_bit_cast(bf16x8, u32x4{w[4], w[5], w[6], w[7]});

            // PV: A = V^T (rows=d), B = P; k-slots st*4..st*4+3
            __builtin_amdgcn_s_setprio(1);
            #pragma unroll
            for (int dt = 0; dt < 8; dt++) {
                const int d = dt * 32 + r32;
                const int sw = d & 7;
                bf16x8 v0 = *(const bf16x8*)(vb + d * 128
                               + (((st * 4 + h)     ^ sw) * 16));
                bf16x8 v1 = *(const bf16x8*)(vb + d * 128
                               + (((st * 4 + 2 + h) ^ sw) * 16));
                f32x16 oo = o[dt];
                if (!defer) {
                    #pragma unroll
                    for (int j = 0; j < 16; j++) oo[j] *= sc;
                }
                oo = MFMAPV(v0, pA, oo);
                oo = MFMAPV(v1, pB, oo);
                o[dt] = oo;
            }
            __builtin_amdgcn_s_setprio(0);
        }

        __syncthreads();   // drains vmcnt: prefetch landed; buffers reusable
    }

    // ---- m,l store ----
    if (h == 0) {
        float2* mlp = (split == 0) ? ml0 : (split == 1) ? ml1
                    : (split == 2) ? ml2 : ml3;
        mlp[qrow0 + wid * 32 + r32] = float2{m_run, l_run};
    }

    // ---- epilogue: LDS transpose (32-d passes) + coalesced bf16 store ----
    unsigned short* oP = (split == 0) ? O0 : (split == 1) ? O1
                       : (split == 2) ? O2 : O3;
    float* T = (float*)smem;   // [256 q][33] f32 = 33 KB
    #pragma unroll
    for (int dt = 0; dt < 8; dt++) {
        __syncthreads();
        #pragma unroll
        for (int j = 0; j < 16; j++) {
            const int dloc = (j & 3) + 8 * (j >> 2) + 4 * h;
            T[(wid * 32 + r32) * 33 + dloc] = o[dt][j];
        }
        __syncthreads();
        #pragma unroll
        for (int rq = 0; rq < 4; rq++) {
            const int q = wid * 32 + rq * 8 + (lane >> 3);
            const float* tr = T + q * 33 + (lane & 7) * 4;
            ushort4t pk;
            #pragma unroll
            for (int r = 0; r < 4; r++) pk[r] = (unsigned short)f2bf(tr[r]);
            *(ushort4t*)(oP + (size_t)(qrow0 + q) * DIM
                         + dt * 32 + (lane & 7) * 4) = pk;
        }
    }
}

// ---------------------------------------------------------------------------
// Kernel 4: merge the four kv-split partials + residual.
// ---------------------------------------------------------------------------
__global__ __launch_bounds__(256) void combine_kernel(
    const unsigned short* __restrict__ o0, const unsigned short* __restrict__ o1,
    const unsigned short* __restrict__ o2, const unsigned short* __restrict__ o3,
    const float2* __restrict__ ml0, const float2* __restrict__ ml1,
    const float2* __restrict__ ml2, const float2* __restrict__ ml3,
    const float* __restrict__ x, float* __restrict__ out)
{
    int row = blockIdx.x * 4 + (threadIdx.x >> 6);
    int c0  = (threadIdx.x & 63) * 4;
    float2 A = ml0[row], B = ml1[row], C = ml2[row], D = ml3[row];
    float M  = fmaxf(fmaxf(A.x, B.x), fmaxf(C.x, D.x));
    float w0 = __expf(A.x - M), w1 = __expf(B.x - M);
    float w2 = __expf(C.x - M), w3 = __expf(D.x - M);
    float inv = 1.0f / (w0 * A.y + w1 * B.y + w2 * C.y + w3 * D.y);
    size_t base = (size_t)row * DIM + c0;
    ushort4t u0 = *(const ushort4t*)(o0 + base);
    ushort4t u1 = *(const ushort4t*)(o1 + base);
    ushort4t u2 = *(const ushort4t*)(o2 + base);
    ushort4t u3 = *(const ushort4t*)(o3 + base);
    f32x4    xr = *(const f32x4*)(x + base);
    f32x4 res;
    #pragma unroll
    for (int j = 0; j < 4; j++)
        res[j] = (w0 * bf2f((unsigned)u0[j]) + w1 * bf2f((unsigned)u1[j])
                + w2 * bf2f((unsigned)u2[j]) + w3 * bf2f((unsigned)u3[j])) * inv
                + xr[j];
    *(f32x4*)(out + base) = res;
}

// ---------------------------------------------------------------------------
extern "C" void kernel_launch(void* const* d_in, const int* in_sizes, int n_in,
                              void* d_out, int out_size, void* d_ws, size_t ws_size,
                              hipStream_t stream)
{
    const float* x  = (const float*)d_in[0];
    const float* Wq = (const float*)d_in[1];
    const float* bq = (const float*)d_in[2];
    const float* Wk = (const float*)d_in[3];
    const float* bk = (const float*)d_in[4];
    const float* Wv = (const float*)d_in[5];
    const float* bv = (const float*)d_in[6];
    float* out = (float*)d_out;

    unsigned char* ws = (unsigned char*)d_ws;
    _Float16*       Qf   = (_Float16*)(ws);                      //  8 MB
    _Float16*       Kf   = (_Float16*)(ws +  8388608);           //  8 MB
    unsigned short* Vt   = (unsigned short*)(ws + 16777216);     //  8 MB
    unsigned short* WtHi = (unsigned short*)(ws + 25165824);     // 384 KB
    unsigned short* WtLo = (unsigned short*)(ws + 25559040);     // 384 KB
    unsigned short* O0   = (unsigned short*)(ws + 25952256);     //  8 MB
    unsigned short* O1   = (unsigned short*)(ws + 34340864);     //  8 MB
    unsigned short* O2   = (unsigned short*)(ws + 42729472);     //  8 MB
    unsigned short* O3   = (unsigned short*)(ws + 51118080);     //  8 MB
    float2*         ML0  = (float2*)       (ws + 59506688);
    float2*         ML1  = (float2*)       (ws + 59637760);
    float2*         ML2  = (float2*)       (ws + 59768832);
    float2*         ML3  = (float2*)       (ws + 59899904);
    // total ws use: 60,030,976 bytes

    convert_w_kernel<<<dim3(256, 3), 256, 0, stream>>>(Wq, Wk, Wv, WtHi, WtLo);
    proj_kernel<<<dim3(256, 2), 256, 0, stream>>>(x, WtHi, WtLo, bq, bk, bv,
                                                  Qf, Kf, Vt);
    flash_kernel<<<dim3(64, 4), 512, 0, stream>>>(Qf, Kf, Vt,
                                                  O0, O1, O2, O3,
                                                  ML0, ML1, ML2, ML3);
    combine_kernel<<<4096, 256, 0, stream>>>(O0, O1, O2, O3,
                                             ML0, ML1, ML2, ML3, x, out);
}

// Round 12
// 163.116 us; speedup vs baseline: 1.1594x; 1.1594x over previous
//
#include <hip/hip_runtime.h>
#include <stdint.h>

#define NB   4
#define SEQ  4096
#define DIM  256
#define NROW (NB*SEQ)   // 16384

using bf16x8   = __attribute__((ext_vector_type(8))) __bf16;
using half8    = __attribute__((ext_vector_type(8))) _Float16;
using f32x4    = __attribute__((ext_vector_type(4))) float;
using f32x16   = __attribute__((ext_vector_type(16))) float;
using u32x4    = __attribute__((ext_vector_type(4))) unsigned int;
using ushort4t = __attribute__((ext_vector_type(4))) unsigned short;

__device__ __forceinline__ unsigned f2bf(float f){
    unsigned u = __builtin_bit_cast(unsigned, f);
    return (u + 0x7fffu + ((u >> 16) & 1u)) >> 16;   // RNE to bf16 bits
}
__device__ __forceinline__ float bf2f(unsigned b){
    return __builtin_bit_cast(float, b << 16);
}

#define MFMA(a,b,c)   __builtin_amdgcn_mfma_f32_16x16x32_bf16((a),(b),(c),0,0,0)
#define MFMAQK(a,b,c) __builtin_amdgcn_mfma_f32_32x32x16_f16((a),(b),(c),0,0,0)
#define MFMAPV(a,b,c) __builtin_amdgcn_mfma_f32_32x32x16_bf16((a),(b),(c),0,0,0)

// async global -> LDS, 16 B per lane. LDS dest = wave-uniform base + lane*16.
__device__ __forceinline__ void gld16(const void* g, void* l){
    __builtin_amdgcn_global_load_lds(
        (const __attribute__((address_space(1))) void*)g,
        (__attribute__((address_space(3))) void*)l, 16, 0, 0);
}

// ---------------------------------------------------------------------------
// Kernel 1: W[k][n] fp32 -> FRAGMENT-ORDERED split bf16 planes.
//   o = ((((m*2+nh)*8+nt)*8+kc)*64 + lane)*8 + j
// ---------------------------------------------------------------------------
__global__ __launch_bounds__(256) void convert_w_kernel(
    const float* __restrict__ Wq, const float* __restrict__ Wk,
    const float* __restrict__ Wv,
    unsigned short* __restrict__ WtHi, unsigned short* __restrict__ WtLo)
{
    int mat = blockIdx.y;
    const float* W = (mat == 0) ? Wq : (mat == 1 ? Wk : Wv);
    int id = blockIdx.x * 256 + threadIdx.x;     // 0..65535
    int k = id >> 8, n = id & 255;
    float v = W[id];                              // W[k][n], coalesced read
    unsigned hi = f2bf(v);
    unsigned lo = f2bf(v - bf2f(hi));
    int nh = n >> 7, nt = (n >> 4) & 7, q16 = n & 15;
    int kc = k >> 5, g = (k >> 3) & 3, j = k & 7;
    int lane = g * 16 + q16;
    int o = ((((mat * 2 + nh) * 8 + nt) * 8 + kc) * 64 + lane) * 8 + j;
    WtHi[o] = (unsigned short)hi;
    WtLo[o] = (unsigned short)lo;
}

// ---------------------------------------------------------------------------
// Kernel 2: fused QKV projection (3-term bf16 split, fp32 accum).
// W fragments staged per-kc into 48 KB LDS via global_load_lds (R11-proven:
// one copy per block instead of per wave -> proj ~55 -> ~26 us).
// Emits Qf/Kf fp16 [16384][256], Vt bf16 transposed [b][d][s].
// ---------------------------------------------------------------------------
__global__ __launch_bounds__(256) void proj_kernel(
    const float* __restrict__ x,
    const unsigned short* __restrict__ WtHi, const unsigned short* __restrict__ WtLo,
    const float* __restrict__ bq, const float* __restrict__ bk,
    const float* __restrict__ bv,
    _Float16* __restrict__ Qf, _Float16* __restrict__ Kf,
    unsigned short* __restrict__ Vt)
{
    __shared__ __align__(16) unsigned char wsm[49152];   // 48 frag-slots x 1 KB

    const int tid = threadIdx.x, lane = tid & 63, wid = tid >> 6;
    const int g = lane >> 4, q16 = lane & 15;
    const int mbase = blockIdx.x * 64 + wid * 16;
    const int nh = blockIdx.y;

    f32x4 acc[3][8];
    #pragma unroll
    for (int m = 0; m < 3; m++)
        #pragma unroll
        for (int n = 0; n < 8; n++) acc[m][n] = f32x4{0.f, 0.f, 0.f, 0.f};

    const float* xr = x + (mbase + q16) * DIM;

    for (int kc = 0; kc < 8; kc++) {
        __syncthreads();   // previous iteration's LDS reads complete
        // ---- stage this kc's 48 fragment-KB (3 mats x 8 nt x 2 planes) ----
        #pragma unroll
        for (int i = 0; i < 12; i++) {
            const int idx = wid * 12 + i;            // 0..47 = mat*16+nt*2+pl
            const int mat = idx >> 4, nt = (idx >> 1) & 7, pl = idx & 1;
            const size_t fb =
                ((size_t)(((mat * 2 + nh) * 8 + nt) * 8 + kc)) * 512 + lane * 8;
            gld16((pl ? WtLo : WtHi) + fb, wsm + idx * 1024);
        }

        // ---- x split hi/lo (overlaps the DMA) ----
        const float* p = xr + kc * 32 + 8 * g;
        f32x4 va = *(const f32x4*)p;
        f32x4 vb = *(const f32x4*)(p + 4);
        float fv[8] = {va[0], va[1], va[2], va[3], vb[0], vb[1], vb[2], vb[3]};
        unsigned hw[4], lw[4];
        #pragma unroll
        for (int i = 0; i < 4; i++) {
            unsigned h0 = f2bf(fv[2*i]),              h1 = f2bf(fv[2*i+1]);
            unsigned l0 = f2bf(fv[2*i]   - bf2f(h0)), l1 = f2bf(fv[2*i+1] - bf2f(h1));
            hw[i] = h0 | (h1 << 16);
            lw[i] = l0 | (l1 << 16);
        }
        bf16x8 ahi = __builtin_bit_cast(bf16x8, u32x4{hw[0], hw[1], hw[2], hw[3]});
        bf16x8 alo = __builtin_bit_cast(bf16x8, u32x4{lw[0], lw[1], lw[2], lw[3]});

        __syncthreads();   // DMA landed (barrier drains vmcnt)

        #pragma unroll
        for (int mat = 0; mat < 3; mat++) {
            #pragma unroll
            for (int nt = 0; nt < 8; nt++) {
                const int sidx = mat * 16 + nt * 2;
                bf16x8 bh = *(const bf16x8*)(wsm + sidx * 1024 + lane * 16);
                bf16x8 bl = *(const bf16x8*)(wsm + (sidx + 1) * 1024 + lane * 16);
                acc[mat][nt] = MFMA(ahi, bh, acc[mat][nt]);
                acc[mat][nt] = MFMA(ahi, bl, acc[mat][nt]);
                acc[mat][nt] = MFMA(alo, bh, acc[mat][nt]);
            }
        }
    }

    #pragma unroll
    for (int nt = 0; nt < 8; nt++) {
        int ncol = nh * 128 + nt * 16 + q16;
        {   // Q -> fp16
            float bb = bq[ncol];
            f32x4 c = acc[0][nt];
            #pragma unroll
            for (int r = 0; r < 4; r++)
                Qf[(size_t)(mbase + 4*g + r) * DIM + ncol] = (_Float16)(c[r] + bb);
        }
        {   // K -> fp16
            float bb = bk[ncol];
            f32x4 c = acc[1][nt];
            #pragma unroll
            for (int r = 0; r < 4; r++)
                Kf[(size_t)(mbase + 4*g + r) * DIM + ncol] = (_Float16)(c[r] + bb);
        }
        {   // V -> plain transposed bf16 Vt[b][d][s]
            float bb = bv[ncol];
            f32x4 c = acc[2][nt];
            ushort4t pk;
            #pragma unroll
            for (int r = 0; r < 4; r++) pk[r] = (unsigned short)f2bf(c[r] + bb);
            int m0 = mbase + 4 * g;
            int bat = m0 >> 12, s0 = m0 & 4095;
            *(ushort4t*)(Vt + (size_t)(bat * DIM + ncol) * SEQ + s0) = pk;
        }
    }
}

// ---------------------------------------------------------------------------
// Kernel 3: flash attention — VERBATIM R10 (known-best, 111 us).
// 8 waves x 32 q-rows = 256 rows/block. grid (64 qtiles, 4 splits) = 256
// blocks = 1/CU. KVBLK=64, wave-staggered sub-tile order, single MFMA chain.
// (R9/R11 lesson: do NOT hand-reorder this schedule — both attempts lost
// ~25%. The compiler + 2-waves/SIMD co-issue already schedule it well.)
// LDS: K 32KB + V 32KB per buffer, double-buffered.
// ---------------------------------------------------------------------------
#define KLDS  0
#define VLDS  32768
#define BUFSZ 65536

__global__ __launch_bounds__(512, 1) void flash_kernel(
    const _Float16* __restrict__ Qf, const _Float16* __restrict__ Kf,
    const unsigned short* __restrict__ Vt,
    unsigned short* __restrict__ O0, unsigned short* __restrict__ O1,
    unsigned short* __restrict__ O2, unsigned short* __restrict__ O3,
    float2* __restrict__ ml0, float2* __restrict__ ml1,
    float2* __restrict__ ml2, float2* __restrict__ ml3)
{
    __shared__ __align__(16) unsigned char smem[131072];

    const int tid = threadIdx.x, lane = tid & 63, wid = tid >> 6;
    const int r32 = lane & 31, h = lane >> 5;
    const int qrow0 = blockIdx.x * 256;
    const int b = qrow0 >> 12;
    const int split = blockIdx.y;
    const int kvbase = split * 1024;
    const int stp = wid & 1;          // sub-tile phase stagger per wave

    // --- Q fragments: B-operand, col q = r32, k = 16s + 8h + j ---
    half8 qf[16];
    {
        const _Float16* qp = Qf + (size_t)(qrow0 + wid * 32 + r32) * DIM;
        #pragma unroll
        for (int s = 0; s < 16; s++)
            qf[s] = *(const half8*)(qp + s * 16 + h * 8);
    }

    f32x16 o[8];
    #pragma unroll
    for (int i = 0; i < 8; i++)
        #pragma unroll
        for (int j = 0; j < 16; j++) o[i][j] = 0.f;
    float m_run = -3.0e38f, l_run = 0.f;

    // ---- staging: 8 x global_load_lds per wave per KVBLK (64 total) ----
    auto stage = [&](int chunk, int buf) {
        const int kv0 = kvbase + chunk * 64;
        unsigned char* base = smem + buf * BUFSZ;
        #pragma unroll
        for (int i = 0; i < 4; i++) {
            const int t = wid * 4 + i;                 // 0..31
            // K fp16 [64 rows][512B]; instr t covers rows 2t,2t+1
            const int krow = 2 * t + h;
            const int ksl  = (lane & 31) ^ (krow & 7);
            gld16(Kf + (size_t)(b * SEQ + kv0 + krow) * DIM + ksl * 8,
                  base + KLDS + t * 1024);
            // V bf16 [256 d][128B]; instr t covers d 8t..8t+7
            const int d   = 8 * t + (lane >> 3);
            const int vsl = (lane & 7) ^ (d & 7);
            gld16(Vt + (size_t)(b * DIM + d) * SEQ + kv0 + vsl * 8,
                  base + VLDS + t * 1024);
        }
    };

    stage(0, 0);
    __syncthreads();

    for (int c = 0; c < 16; c++) {
        const int bf = c & 1;
        if (c + 1 < 16) stage(c + 1, bf ^ 1);

        const unsigned char* kb = smem + bf * BUFSZ;
        const unsigned char* vb = kb + VLDS;

        // ---- two 32-kv sub-tiles; order staggered across waves ----
        #pragma unroll
        for (int ii = 0; ii < 2; ii++) {
            const int st = ii ^ stp;
            // QK^T: A = K rows (kv), B = Q (cols=q)
            f32x16 a;
            #pragma unroll
            for (int j = 0; j < 16; j++) a[j] = 0.f;
            __builtin_amdgcn_s_setprio(1);
            #pragma unroll
            for (int s = 0; s < 16; s++) {
                const int off = (st * 32 + r32) * 512
                              + (((2 * s + h) ^ (r32 & 7)) * 16);
                half8 kf = *(const half8*)(kb + KLDS + off);
                a = MFMAQK(kf, qf[s], a);
            }
            __builtin_amdgcn_s_setprio(0);
            // lane holds S[kv=(j&3)+8*(j>>2)+4h (+32*st)][q=r32] in a[j]

            // online softmax (per q-column; halves reduced via xor-32)
            float pm = a[0];
            #pragma unroll
            for (int j = 1; j < 16; j++) pm = fmaxf(pm, a[j]);
            pm = fmaxf(pm, __shfl_xor(pm, 32, 64));
            const bool defer = __all(pm <= m_run + 8.0f) != 0;
            const float mn = defer ? m_run : fmaxf(m_run, pm);
            const float sc = defer ? 1.0f : __expf(m_run - mn);
            float e[16]; float ps = 0.f;
            #pragma unroll
            for (int j = 0; j < 16; j++) { e[j] = __expf(a[j] - mn); ps += e[j]; }
            ps += __shfl_xor(ps, 32, 64);
            l_run = l_run * sc + ps;
            m_run = mn;

            // P -> bf16 B-fragments via cvt_pk + permlane32_swap
            unsigned w[8];
            #pragma unroll
            for (int t = 0; t < 8; t++)
                asm("v_cvt_pk_bf16_f32 %0, %1, %2"
                    : "=v"(w[t]) : "v"(e[2 * t]), "v"(e[2 * t + 1]));
            asm volatile("v_permlane32_swap_b32 %0, %1" : "+v"(w[0]), "+v"(w[2]));
            asm volatile("v_permlane32_swap_b32 %0, %1" : "+v"(w[1]), "+v"(w[3]));
            asm volatile("v_permlane32_swap_b32 %0, %1" : "+v"(w[4]), "+v"(w[6]));
            asm volatile("v_permlane32_swap_b32 %0, %1" : "+v"(w[5]), "+v"(w[7]));
            bf16x8 pA = __builtin_bit_cast(bf16x8, u32x4{w[0], w[1], w[2], w[3]});
            bf16x8 pB = __builtin_bit_cast(bf16x8, u32x4{w[4], w[5], w[6], w[7]});

            // PV: A = V^T (rows=d), B = P; k-slots st*4..st*4+3
            __builtin_amdgcn_s_setprio(1);
            #pragma unroll
            for (int dt = 0; dt < 8; dt++) {
                const int d = dt * 32 + r32;
                const int sw = d & 7;
                bf16x8 v0 = *(const bf16x8*)(vb + d * 128
                               + (((st * 4 + h)     ^ sw) * 16));
                bf16x8 v1 = *(const bf16x8*)(vb + d * 128
                               + (((st * 4 + 2 + h) ^ sw) * 16));
                f32x16 oo = o[dt];
                if (!defer) {
                    #pragma unroll
                    for (int j = 0; j < 16; j++) oo[j] *= sc;
                }
                oo = MFMAPV(v0, pA, oo);
                oo = MFMAPV(v1, pB, oo);
                o[dt] = oo;
            }
            __builtin_amdgcn_s_setprio(0);
        }

        __syncthreads();   // drains vmcnt: prefetch landed; buffers reusable
    }

    // ---- m,l store ----
    if (h == 0) {
        float2* mlp = (split == 0) ? ml0 : (split == 1) ? ml1
                    : (split == 2) ? ml2 : ml3;
        mlp[qrow0 + wid * 32 + r32] = float2{m_run, l_run};
    }

    // ---- epilogue: LDS transpose (32-d passes) + coalesced bf16 store ----
    unsigned short* oP = (split == 0) ? O0 : (split == 1) ? O1
                       : (split == 2) ? O2 : O3;
    float* T = (float*)smem;   // [256 q][33] f32 = 33 KB
    #pragma unroll
    for (int dt = 0; dt < 8; dt++) {
        __syncthreads();
        #pragma unroll
        for (int j = 0; j < 16; j++) {
            const int dloc = (j & 3) + 8 * (j >> 2) + 4 * h;
            T[(wid * 32 + r32) * 33 + dloc] = o[dt][j];
        }
        __syncthreads();
        #pragma unroll
        for (int rq = 0; rq < 4; rq++) {
            const int q = wid * 32 + rq * 8 + (lane >> 3);
            const float* tr = T + q * 33 + (lane & 7) * 4;
            ushort4t pk;
            #pragma unroll
            for (int r = 0; r < 4; r++) pk[r] = (unsigned short)f2bf(tr[r]);
            *(ushort4t*)(oP + (size_t)(qrow0 + q) * DIM
                         + dt * 32 + (lane & 7) * 4) = pk;
        }
    }
}

// ---------------------------------------------------------------------------
// Kernel 4: merge the four kv-split partials + residual.
// ---------------------------------------------------------------------------
__global__ __launch_bounds__(256) void combine_kernel(
    const unsigned short* __restrict__ o0, const unsigned short* __restrict__ o1,
    const unsigned short* __restrict__ o2, const unsigned short* __restrict__ o3,
    const float2* __restrict__ ml0, const float2* __restrict__ ml1,
    const float2* __restrict__ ml2, const float2* __restrict__ ml3,
    const float* __restrict__ x, float* __restrict__ out)
{
    int row = blockIdx.x * 4 + (threadIdx.x >> 6);
    int c0  = (threadIdx.x & 63) * 4;
    float2 A = ml0[row], B = ml1[row], C = ml2[row], D = ml3[row];
    float M  = fmaxf(fmaxf(A.x, B.x), fmaxf(C.x, D.x));
    float w0 = __expf(A.x - M), w1 = __expf(B.x - M);
    float w2 = __expf(C.x - M), w3 = __expf(D.x - M);
    float inv = 1.0f / (w0 * A.y + w1 * B.y + w2 * C.y + w3 * D.y);
    size_t base = (size_t)row * DIM + c0;
    ushort4t u0 = *(const ushort4t*)(o0 + base);
    ushort4t u1 = *(const ushort4t*)(o1 + base);
    ushort4t u2 = *(const ushort4t*)(o2 + base);
    ushort4t u3 = *(const ushort4t*)(o3 + base);
    f32x4    xr = *(const f32x4*)(x + base);
    f32x4 res;
    #pragma unroll
    for (int j = 0; j < 4; j++)
        res[j] = (w0 * bf2f((unsigned)u0[j]) + w1 * bf2f((unsigned)u1[j])
                + w2 * bf2f((unsigned)u2[j]) + w3 * bf2f((unsigned)u3[j])) * inv
                + xr[j];
    *(f32x4*)(out + base) = res;
}

// ---------------------------------------------------------------------------
extern "C" void kernel_launch(void* const* d_in, const int* in_sizes, int n_in,
                              void* d_out, int out_size, void* d_ws, size_t ws_size,
                              hipStream_t stream)
{
    const float* x  = (const float*)d_in[0];
    const float* Wq = (const float*)d_in[1];
    const float* bq = (const float*)d_in[2];
    const float* Wk = (const float*)d_in[3];
    const float* bk = (const float*)d_in[4];
    const float* Wv = (const float*)d_in[5];
    const float* bv = (const float*)d_in[6];
    float* out = (float*)d_out;

    unsigned char* ws = (unsigned char*)d_ws;
    _Float16*       Qf   = (_Float16*)(ws);                      //  8 MB
    _Float16*       Kf   = (_Float16*)(ws +  8388608);           //  8 MB
    unsigned short* Vt   = (unsigned short*)(ws + 16777216);     //  8 MB
    unsigned short* WtHi = (unsigned short*)(ws + 25165824);     // 384 KB
    unsigned short* WtLo = (unsigned short*)(ws + 25559040);     // 384 KB
    unsigned short* O0   = (unsigned short*)(ws + 25952256);     //  8 MB
    unsigned short* O1   = (unsigned short*)(ws + 34340864);     //  8 MB
    unsigned short* O2   = (unsigned short*)(ws + 42729472);     //  8 MB
    unsigned short* O3   = (unsigned short*)(ws + 51118080);     //  8 MB
    float2*         ML0  = (float2*)       (ws + 59506688);
    float2*         ML1  = (float2*)       (ws + 59637760);
    float2*         ML2  = (float2*)       (ws + 59768832);
    float2*         ML3  = (float2*)       (ws + 59899904);
    // total ws use: 60,030,976 bytes

    convert_w_kernel<<<dim3(256, 3), 256, 0, stream>>>(Wq, Wk, Wv, WtHi, WtLo);
    proj_kernel<<<dim3(256, 2), 256, 0, stream>>>(x, WtHi, WtLo, bq, bk, bv,
                                                  Qf, Kf, Vt);
    flash_kernel<<<dim3(64, 4), 512, 0, stream>>>(Qf, Kf, Vt,
                                                  O0, O1, O2, O3,
                                                  ML0, ML1, ML2, ML3);
    combine_kernel<<<4096, 256, 0, stream>>>(O0, O1, O2, O3,
                                             ML0, ML1, ML2, ML3, x, out);
}

// Round 13
// 156.471 us; speedup vs baseline: 1.2086x; 1.0425x over previous
//
#include <hip/hip_runtime.h>
#include <stdint.h>

#define NB   4
#define SEQ  4096
#define DIM  256
#define NROW (NB*SEQ)   // 16384

using bf16x8   = __attribute__((ext_vector_type(8))) __bf16;
using half8    = __attribute__((ext_vector_type(8))) _Float16;
using f32x4    = __attribute__((ext_vector_type(4))) float;
using f32x16   = __attribute__((ext_vector_type(16))) float;
using u32x4    = __attribute__((ext_vector_type(4))) unsigned int;
using ushort4t = __attribute__((ext_vector_type(4))) unsigned short;

__device__ __forceinline__ unsigned f2bf(float f){
    unsigned u = __builtin_bit_cast(unsigned, f);
    return (u + 0x7fffu + ((u >> 16) & 1u)) >> 16;   // RNE to bf16 bits
}
__device__ __forceinline__ float bf2f(unsigned b){
    return __builtin_bit_cast(float, b << 16);
}

#define MFMA(a,b,c)   __builtin_amdgcn_mfma_f32_16x16x32_bf16((a),(b),(c),0,0,0)
#define MFMAQK(a,b,c) __builtin_amdgcn_mfma_f32_32x32x16_f16((a),(b),(c),0,0,0)
#define MFMAPV(a,b,c) __builtin_amdgcn_mfma_f32_32x32x16_bf16((a),(b),(c),0,0,0)

// async global -> LDS, 16 B per lane. LDS dest = wave-uniform base + lane*16.
__device__ __forceinline__ void gld16(const void* g, void* l){
    __builtin_amdgcn_global_load_lds(
        (const __attribute__((address_space(1))) void*)g,
        (__attribute__((address_space(3))) void*)l, 16, 0, 0);
}

// Cross-half (lane i <-> i+32) reduce on the VALU pipe via permlane32_swap.
// CRITICAL (R8 lesson): b must be forced into its OWN register — if a and b
// are the same SSA value the compiler CSEs them, regalloc ties both "+v"
// operands to one physreg, and the swap becomes an in-place half-exchange
// (wrong). The empty asm makes b opaque-but-equal -> two live values ->
// distinct physregs. After swap(a,b): every lane holds its own value in one
// reg and the cross-half value in the other.
__device__ __forceinline__ float xhalf_max(float x){
    unsigned a = __builtin_bit_cast(unsigned, x);
    unsigned b = a;
    asm volatile("" : "+v"(b));                       // force distinct reg
    asm volatile("v_permlane32_swap_b32 %0, %1" : "+v"(a), "+v"(b));
    return fmaxf(__builtin_bit_cast(float, a), __builtin_bit_cast(float, b));
}
__device__ __forceinline__ float xhalf_sum(float x){
    unsigned a = __builtin_bit_cast(unsigned, x);
    unsigned b = a;
    asm volatile("" : "+v"(b));                       // force distinct reg
    asm volatile("v_permlane32_swap_b32 %0, %1" : "+v"(a), "+v"(b));
    return __builtin_bit_cast(float, a) + __builtin_bit_cast(float, b);
}

// ---------------------------------------------------------------------------
// Kernel 1: W[k][n] fp32 -> FRAGMENT-ORDERED split bf16 planes.
//   o = ((((m*2+nh)*8+nt)*8+kc)*64 + lane)*8 + j
// ---------------------------------------------------------------------------
__global__ __launch_bounds__(256) void convert_w_kernel(
    const float* __restrict__ Wq, const float* __restrict__ Wk,
    const float* __restrict__ Wv,
    unsigned short* __restrict__ WtHi, unsigned short* __restrict__ WtLo)
{
    int mat = blockIdx.y;
    const float* W = (mat == 0) ? Wq : (mat == 1 ? Wk : Wv);
    int id = blockIdx.x * 256 + threadIdx.x;     // 0..65535
    int k = id >> 8, n = id & 255;
    float v = W[id];                              // W[k][n], coalesced read
    unsigned hi = f2bf(v);
    unsigned lo = f2bf(v - bf2f(hi));
    int nh = n >> 7, nt = (n >> 4) & 7, q16 = n & 15;
    int kc = k >> 5, g = (k >> 3) & 3, j = k & 7;
    int lane = g * 16 + q16;
    int o = ((((mat * 2 + nh) * 8 + nt) * 8 + kc) * 64 + lane) * 8 + j;
    WtHi[o] = (unsigned short)hi;
    WtLo[o] = (unsigned short)lo;
}

// ---------------------------------------------------------------------------
// Kernel 2: fused QKV projection (3-term bf16 split, fp32 accum) — verbatim
// R12. W fragments staged per-kc into 48 KB LDS via global_load_lds.
// Emits Qf/Kf fp16 [16384][256], Vt bf16 transposed [b][d][s].
// ---------------------------------------------------------------------------
__global__ __launch_bounds__(256) void proj_kernel(
    const float* __restrict__ x,
    const unsigned short* __restrict__ WtHi, const unsigned short* __restrict__ WtLo,
    const float* __restrict__ bq, const float* __restrict__ bk,
    const float* __restrict__ bv,
    _Float16* __restrict__ Qf, _Float16* __restrict__ Kf,
    unsigned short* __restrict__ Vt)
{
    __shared__ __align__(16) unsigned char wsm[49152];   // 48 frag-slots x 1 KB

    const int tid = threadIdx.x, lane = tid & 63, wid = tid >> 6;
    const int g = lane >> 4, q16 = lane & 15;
    const int mbase = blockIdx.x * 64 + wid * 16;
    const int nh = blockIdx.y;

    f32x4 acc[3][8];
    #pragma unroll
    for (int m = 0; m < 3; m++)
        #pragma unroll
        for (int n = 0; n < 8; n++) acc[m][n] = f32x4{0.f, 0.f, 0.f, 0.f};

    const float* xr = x + (mbase + q16) * DIM;

    for (int kc = 0; kc < 8; kc++) {
        __syncthreads();   // previous iteration's LDS reads complete
        // ---- stage this kc's 48 fragment-KB (3 mats x 8 nt x 2 planes) ----
        #pragma unroll
        for (int i = 0; i < 12; i++) {
            const int idx = wid * 12 + i;            // 0..47 = mat*16+nt*2+pl
            const int mat = idx >> 4, nt = (idx >> 1) & 7, pl = idx & 1;
            const size_t fb =
                ((size_t)(((mat * 2 + nh) * 8 + nt) * 8 + kc)) * 512 + lane * 8;
            gld16((pl ? WtLo : WtHi) + fb, wsm + idx * 1024);
        }

        // ---- x split hi/lo (overlaps the DMA) ----
        const float* p = xr + kc * 32 + 8 * g;
        f32x4 va = *(const f32x4*)p;
        f32x4 vb = *(const f32x4*)(p + 4);
        float fv[8] = {va[0], va[1], va[2], va[3], vb[0], vb[1], vb[2], vb[3]};
        unsigned hw[4], lw[4];
        #pragma unroll
        for (int i = 0; i < 4; i++) {
            unsigned h0 = f2bf(fv[2*i]),              h1 = f2bf(fv[2*i+1]);
            unsigned l0 = f2bf(fv[2*i]   - bf2f(h0)), l1 = f2bf(fv[2*i+1] - bf2f(h1));
            hw[i] = h0 | (h1 << 16);
            lw[i] = l0 | (l1 << 16);
        }
        bf16x8 ahi = __builtin_bit_cast(bf16x8, u32x4{hw[0], hw[1], hw[2], hw[3]});
        bf16x8 alo = __builtin_bit_cast(bf16x8, u32x4{lw[0], lw[1], lw[2], lw[3]});

        __syncthreads();   // DMA landed (barrier drains vmcnt)

        #pragma unroll
        for (int mat = 0; mat < 3; mat++) {
            #pragma unroll
            for (int nt = 0; nt < 8; nt++) {
                const int sidx = mat * 16 + nt * 2;
                bf16x8 bh = *(const bf16x8*)(wsm + sidx * 1024 + lane * 16);
                bf16x8 bl = *(const bf16x8*)(wsm + (sidx + 1) * 1024 + lane * 16);
                acc[mat][nt] = MFMA(ahi, bh, acc[mat][nt]);
                acc[mat][nt] = MFMA(ahi, bl, acc[mat][nt]);
                acc[mat][nt] = MFMA(alo, bh, acc[mat][nt]);
            }
        }
    }

    #pragma unroll
    for (int nt = 0; nt < 8; nt++) {
        int ncol = nh * 128 + nt * 16 + q16;
        {   // Q -> fp16
            float bb = bq[ncol];
            f32x4 c = acc[0][nt];
            #pragma unroll
            for (int r = 0; r < 4; r++)
                Qf[(size_t)(mbase + 4*g + r) * DIM + ncol] = (_Float16)(c[r] + bb);
        }
        {   // K -> fp16
            float bb = bk[ncol];
            f32x4 c = acc[1][nt];
            #pragma unroll
            for (int r = 0; r < 4; r++)
                Kf[(size_t)(mbase + 4*g + r) * DIM + ncol] = (_Float16)(c[r] + bb);
        }
        {   // V -> plain transposed bf16 Vt[b][d][s]
            float bb = bv[ncol];
            f32x4 c = acc[2][nt];
            ushort4t pk;
            #pragma unroll
            for (int r = 0; r < 4; r++) pk[r] = (unsigned short)f2bf(c[r] + bb);
            int m0 = mbase + 4 * g;
            int bat = m0 >> 12, s0 = m0 & 4095;
            *(ushort4t*)(Vt + (size_t)(bat * DIM + ncol) * SEQ + s0) = pk;
        }
    }
}

// ---------------------------------------------------------------------------
// Kernel 3: flash attention — R10/R12 structure (known-best schedule).
// SINGLE change vs R12: cross-half softmax reduces moved from __shfl_xor
// (DS crossbar) to permlane32_swap (VALU) with the opaque-register fix.
// Math is identical; DS-pipe load drops ~2k cy/chunk/CU.
// 8 waves x 32 q-rows; grid (64 qtiles, 4 splits) = 256 blocks = 1/CU.
// KVBLK=64, wave-staggered sub-tile order, single MFMA chain.
// LDS: K 32KB + V 32KB per buffer, double-buffered.
// ---------------------------------------------------------------------------
#define KLDS  0
#define VLDS  32768
#define BUFSZ 65536

__global__ __launch_bounds__(512, 1) void flash_kernel(
    const _Float16* __restrict__ Qf, const _Float16* __restrict__ Kf,
    const unsigned short* __restrict__ Vt,
    unsigned short* __restrict__ O0, unsigned short* __restrict__ O1,
    unsigned short* __restrict__ O2, unsigned short* __restrict__ O3,
    float2* __restrict__ ml0, float2* __restrict__ ml1,
    float2* __restrict__ ml2, float2* __restrict__ ml3)
{
    __shared__ __align__(16) unsigned char smem[131072];

    const int tid = threadIdx.x, lane = tid & 63, wid = tid >> 6;
    const int r32 = lane & 31, h = lane >> 5;
    const int qrow0 = blockIdx.x * 256;
    const int b = qrow0 >> 12;
    const int split = blockIdx.y;
    const int kvbase = split * 1024;
    const int stp = wid & 1;          // sub-tile phase stagger per wave

    // --- Q fragments: B-operand, col q = r32, k = 16s + 8h + j ---
    half8 qf[16];
    {
        const _Float16* qp = Qf + (size_t)(qrow0 + wid * 32 + r32) * DIM;
        #pragma unroll
        for (int s = 0; s < 16; s++)
            qf[s] = *(const half8*)(qp + s * 16 + h * 8);
    }

    f32x16 o[8];
    #pragma unroll
    for (int i = 0; i < 8; i++)
        #pragma unroll
        for (int j = 0; j < 16; j++) o[i][j] = 0.f;
    float m_run = -3.0e38f, l_run = 0.f;

    // ---- staging: 8 x global_load_lds per wave per KVBLK (64 total) ----
    auto stage = [&](int chunk, int buf) {
        const int kv0 = kvbase + chunk * 64;
        unsigned char* base = smem + buf * BUFSZ;
        #pragma unroll
        for (int i = 0; i < 4; i++) {
            const int t = wid * 4 + i;                 // 0..31
            // K fp16 [64 rows][512B]; instr t covers rows 2t,2t+1
            const int krow = 2 * t + h;
            const int ksl  = (lane & 31) ^ (krow & 7);
            gld16(Kf + (size_t)(b * SEQ + kv0 + krow) * DIM + ksl * 8,
                  base + KLDS + t * 1024);
            // V bf16 [256 d][128B]; instr t covers d 8t..8t+7
            const int d   = 8 * t + (lane >> 3);
            const int vsl = (lane & 7) ^ (d & 7);
            gld16(Vt + (size_t)(b * DIM + d) * SEQ + kv0 + vsl * 8,
                  base + VLDS + t * 1024);
        }
    };

    stage(0, 0);
    __syncthreads();

    for (int c = 0; c < 16; c++) {
        const int bf = c & 1;
        if (c + 1 < 16) stage(c + 1, bf ^ 1);

        const unsigned char* kb = smem + bf * BUFSZ;
        const unsigned char* vb = kb + VLDS;

        // ---- two 32-kv sub-tiles; order staggered across waves ----
        #pragma unroll
        for (int ii = 0; ii < 2; ii++) {
            const int st = ii ^ stp;
            // QK^T: A = K rows (kv), B = Q (cols=q)
            f32x16 a;
            #pragma unroll
            for (int j = 0; j < 16; j++) a[j] = 0.f;
            __builtin_amdgcn_s_setprio(1);
            #pragma unroll
            for (int s = 0; s < 16; s++) {
                const int off = (st * 32 + r32) * 512
                              + (((2 * s + h) ^ (r32 & 7)) * 16);
                half8 kf = *(const half8*)(kb + KLDS + off);
                a = MFMAQK(kf, qf[s], a);
            }
            __builtin_amdgcn_s_setprio(0);
            // lane holds S[kv=(j&3)+8*(j>>2)+4h (+32*st)][q=r32] in a[j]

            // online softmax (per q-column; cross-half reduce on VALU)
            float pm = a[0];
            #pragma unroll
            for (int j = 1; j < 16; j++) pm = fmaxf(pm, a[j]);
            pm = xhalf_max(pm);
            const bool defer = __all(pm <= m_run + 8.0f) != 0;
            const float mn = defer ? m_run : fmaxf(m_run, pm);
            const float sc = defer ? 1.0f : __expf(m_run - mn);
            float e[16]; float ps = 0.f;
            #pragma unroll
            for (int j = 0; j < 16; j++) { e[j] = __expf(a[j] - mn); ps += e[j]; }
            ps = xhalf_sum(ps);
            l_run = l_run * sc + ps;
            m_run = mn;

            // P -> bf16 B-fragments via cvt_pk + permlane32_swap
            unsigned w[8];
            #pragma unroll
            for (int t = 0; t < 8; t++)
                asm("v_cvt_pk_bf16_f32 %0, %1, %2"
                    : "=v"(w[t]) : "v"(e[2 * t]), "v"(e[2 * t + 1]));
            asm volatile("v_permlane32_swap_b32 %0, %1" : "+v"(w[0]), "+v"(w[2]));
            asm volatile("v_permlane32_swap_b32 %0, %1" : "+v"(w[1]), "+v"(w[3]));
            asm volatile("v_permlane32_swap_b32 %0, %1" : "+v"(w[4]), "+v"(w[6]));
            asm volatile("v_permlane32_swap_b32 %0, %1" : "+v"(w[5]), "+v"(w[7]));
            bf16x8 pA = __builtin_bit_cast(bf16x8, u32x4{w[0], w[1], w[2], w[3]});
            bf16x8 pB = __builtin_bit_cast(bf16x8, u32x4{w[4], w[5], w[6], w[7]});

            // PV: A = V^T (rows=d), B = P; k-slots st*4..st*4+3
            __builtin_amdgcn_s_setprio(1);
            #pragma unroll
            for (int dt = 0; dt < 8; dt++) {
                const int d = dt * 32 + r32;
                const int sw = d & 7;
                bf16x8 v0 = *(const bf16x8*)(vb + d * 128
                               + (((st * 4 + h)     ^ sw) * 16));
                bf16x8 v1 = *(const bf16x8*)(vb + d * 128
                               + (((st * 4 + 2 + h) ^ sw) * 16));
                f32x16 oo = o[dt];
                if (!defer) {
                    #pragma unroll
                    for (int j = 0; j < 16; j++) oo[j] *= sc;
                }
                oo = MFMAPV(v0, pA, oo);
                oo = MFMAPV(v1, pB, oo);
                o[dt] = oo;
            }
            __builtin_amdgcn_s_setprio(0);
        }

        __syncthreads();   // drains vmcnt: prefetch landed; buffers reusable
    }

    // ---- m,l store ----
    if (h == 0) {
        float2* mlp = (split == 0) ? ml0 : (split == 1) ? ml1
                    : (split == 2) ? ml2 : ml3;
        mlp[qrow0 + wid * 32 + r32] = float2{m_run, l_run};
    }

    // ---- epilogue: LDS transpose (32-d passes) + coalesced bf16 store ----
    unsigned short* oP = (split == 0) ? O0 : (split == 1) ? O1
                       : (split == 2) ? O2 : O3;
    float* T = (float*)smem;   // [256 q][33] f32 = 33 KB
    #pragma unroll
    for (int dt = 0; dt < 8; dt++) {
        __syncthreads();
        #pragma unroll
        for (int j = 0; j < 16; j++) {
            const int dloc = (j & 3) + 8 * (j >> 2) + 4 * h;
            T[(wid * 32 + r32) * 33 + dloc] = o[dt][j];
        }
        __syncthreads();
        #pragma unroll
        for (int rq = 0; rq < 4; rq++) {
            const int q = wid * 32 + rq * 8 + (lane >> 3);
            const float* tr = T + q * 33 + (lane & 7) * 4;
            ushort4t pk;
            #pragma unroll
            for (int r = 0; r < 4; r++) pk[r] = (unsigned short)f2bf(tr[r]);
            *(ushort4t*)(oP + (size_t)(qrow0 + q) * DIM
                         + dt * 32 + (lane & 7) * 4) = pk;
        }
    }
}

// ---------------------------------------------------------------------------
// Kernel 4: merge the four kv-split partials + residual.
// ---------------------------------------------------------------------------
__global__ __launch_bounds__(256) void combine_kernel(
    const unsigned short* __restrict__ o0, const unsigned short* __restrict__ o1,
    const unsigned short* __restrict__ o2, const unsigned short* __restrict__ o3,
    const float2* __restrict__ ml0, const float2* __restrict__ ml1,
    const float2* __restrict__ ml2, const float2* __restrict__ ml3,
    const float* __restrict__ x, float* __restrict__ out)
{
    int row = blockIdx.x * 4 + (threadIdx.x >> 6);
    int c0  = (threadIdx.x & 63) * 4;
    float2 A = ml0[row], B = ml1[row], C = ml2[row], D = ml3[row];
    float M  = fmaxf(fmaxf(A.x, B.x), fmaxf(C.x, D.x));
    float w0 = __expf(A.x - M), w1 = __expf(B.x - M);
    float w2 = __expf(C.x - M), w3 = __expf(D.x - M);
    float inv = 1.0f / (w0 * A.y + w1 * B.y + w2 * C.y + w3 * D.y);
    size_t base = (size_t)row * DIM + c0;
    ushort4t u0 = *(const ushort4t*)(o0 + base);
    ushort4t u1 = *(const ushort4t*)(o1 + base);
    ushort4t u2 = *(const ushort4t*)(o2 + base);
    ushort4t u3 = *(const ushort4t*)(o3 + base);
    f32x4    xr = *(const f32x4*)(x + base);
    f32x4 res;
    #pragma unroll
    for (int j = 0; j < 4; j++)
        res[j] = (w0 * bf2f((unsigned)u0[j]) + w1 * bf2f((unsigned)u1[j])
                + w2 * bf2f((unsigned)u2[j]) + w3 * bf2f((unsigned)u3[j])) * inv
                + xr[j];
    *(f32x4*)(out + base) = res;
}

// ---------------------------------------------------------------------------
extern "C" void kernel_launch(void* const* d_in, const int* in_sizes, int n_in,
                              void* d_out, int out_size, void* d_ws, size_t ws_size,
                              hipStream_t stream)
{
    const float* x  = (const float*)d_in[0];
    const float* Wq = (const float*)d_in[1];
    const float* bq = (const float*)d_in[2];
    const float* Wk = (const float*)d_in[3];
    const float* bk = (const float*)d_in[4];
    const float* Wv = (const float*)d_in[5];
    const float* bv = (const float*)d_in[6];
    float* out = (float*)d_out;

    unsigned char* ws = (unsigned char*)d_ws;
    _Float16*       Qf   = (_Float16*)(ws);                      //  8 MB
    _Float16*       Kf   = (_Float16*)(ws +  8388608);           //  8 MB
    unsigned short* Vt   = (unsigned short*)(ws + 16777216);     //  8 MB
    unsigned short* WtHi = (unsigned short*)(ws + 25165824);     // 384 KB
    unsigned short* WtLo = (unsigned short*)(ws + 25559040);     // 384 KB
    unsigned short* O0   = (unsigned short*)(ws + 25952256);     //  8 MB
    unsigned short* O1   = (unsigned short*)(ws + 34340864);     //  8 MB
    unsigned short* O2   = (unsigned short*)(ws + 42729472);     //  8 MB
    unsigned short* O3   = (unsigned short*)(ws + 51118080);     //  8 MB
    float2*         ML0  = (float2*)       (ws + 59506688);
    float2*         ML1  = (float2*)       (ws + 59637760);
    float2*         ML2  = (float2*)       (ws + 59768832);
    float2*         ML3  = (float2*)       (ws + 59899904);
    // total ws use: 60,030,976 bytes

    convert_w_kernel<<<dim3(256, 3), 256, 0, stream>>>(Wq, Wk, Wv, WtHi, WtLo);
    proj_kernel<<<dim3(256, 2), 256, 0, stream>>>(x, WtHi, WtLo, bq, bk, bv,
                                                  Qf, Kf, Vt);
    flash_kernel<<<dim3(64, 4), 512, 0, stream>>>(Qf, Kf, Vt,
                                                  O0, O1, O2, O3,
                                                  ML0, ML1, ML2, ML3);
    combine_kernel<<<4096, 256, 0, stream>>>(O0, O1, O2, O3,
                                             ML0, ML1, ML2, ML3, x, out);
}